// Round 22
// baseline (363.988 us; speedup 1.0000x reference)
//
#include <hip/hip_runtime.h>

// VectorQuantizer: z [16,1024,512] f32, emb [8192,512] f32
// out: [z_q_st (16384*512 f32)][total_loss (1 f32)][idx as f32 (16384)]
//
// Round 22 = R20 GEMM (no setprio: R21 showed -4%) + grid 1024 (column
// QUARTERS, 8 ct/wave) => 4 blocks/CU instead of 2. B traffic invariant;
// A-register reload doubles (L2-resident). TLP is the session's proven lever
// (R10); occupancy 21% -> ~42%. Finalize = R21's (paired trigger scans kept).

#define N_TOK 16384
#define DIM   512
#define NEMB  8192
#define BETA  0.25f
#define NCT   128            // 64-wide column tiles
#define MARGIN_A 2.4f        // scaled units (acc = 4096*dot); ~8.9 sigma_pair
#define ESCALE 4096.0f
#define NSTAGE 24
#define CLIST  96
#define NTI   8              // col-tiles per wave (quarter = 32 ct / 4 waves)

using f32x4 = __attribute__((ext_vector_type(4))) float;

// ---- ws layout (bytes), total ~44.1 MB ----
#define WS_PMX  0                                  // float4[N_TOK*NCT] = 32MB
#define WS_S1   ((size_t)N_TOK*NCT*16)
#define WS_PART (WS_S1 + N_TOK*4)
#define WS_ZH   (WS_PART + (N_TOK/4)*8)
#define WS_EH   (WS_ZH + (size_t)N_TOK*DIM)

#define GLDS16(g, l) __builtin_amdgcn_global_load_lds( \
    (const __attribute__((address_space(1))) void*)(g), \
    (__attribute__((address_space(3))) void*)(l), 16, 0, 0)

template <int N>
__device__ inline int dpp_ror_i(int v) {            // row_ror:N (16-lane row)
  return __builtin_amdgcn_update_dpp(0, v, 0x120 + N, 0xF, 0xF, false);
}
template <int N>
__device__ inline float dpp_ror_f(float v) {
  return __builtin_bit_cast(float, dpp_ror_i<N>(__builtin_bit_cast(int, v)));
}

// RNE float -> OCP e4m3fn byte (|f| < 448; handles subnormals).
__device__ inline unsigned f2e4m3(float f) {
  unsigned u = __builtin_bit_cast(unsigned, f);
  unsigned s = (u >> 24) & 0x80u;
  float a = __builtin_bit_cast(float, u & 0x7fffffffu);
  if (a < 0.015625f) {
    unsigned q = (unsigned)rintf(a * 512.0f);
    return s | q;
  }
  unsigned m = u & 0x7fffffffu;
  m += 0x7ffffu + ((m >> 20) & 1u);
  unsigned e = (m >> 23) - 127u + 7u;
  return s | (e << 3) | ((m >> 20) & 7u);
}

__device__ inline unsigned pack4(float a, float b, float c, float d) {
  return f2e4m3(a) | (f2e4m3(b) << 8) | (f2e4m3(c) << 16) | (f2e4m3(d) << 24);
}

// Fused pack. zh8: [mt(256)][kc(64)][mi(64)] 8B-units; eh8: [ct(128)][kc(64)][ni(64)].
__global__ void vq_pack(const float* __restrict__ z, const float* __restrict__ emb,
                        unsigned char* __restrict__ zh8, unsigned char* __restrict__ eh8,
                        float* __restrict__ s1) {
  const int w = threadIdx.x >> 6, lane = threadIdx.x & 63;
  if (blockIdx.x < N_TOK / 4) {
    const int row = blockIdx.x * 4 + w;
    const float4* r = (const float4*)(z + (size_t)row * DIM);
    float4 v0 = r[lane * 2], v1 = r[lane * 2 + 1];
    // s1: bit-identical to the round-2 proven path
    float p0=v0.x*v0.x, p1=v0.y*v0.y, p2=v0.z*v0.z, p3=v0.w*v0.w;
    float p4=v1.x*v1.x, p5=v1.y*v1.y, p6=v1.z*v1.z, p7=v1.w*v1.w;
    double s = (double)p0+(double)p1+(double)p2+(double)p3
             + (double)p4+(double)p5+(double)p6+(double)p7;
    #pragma unroll
    for (int m = 32; m >= 1; m >>= 1) s += __shfl_xor(s, m);
    if (lane == 0) s1[row] = (float)s;
    uint2 o;
    o.x = pack4(v0.x, v0.y, v0.z, v0.w);
    o.y = pack4(v1.x, v1.y, v1.z, v1.w);
    const int mt = row >> 6, mi = row & 63;   // kc == lane
    *(uint2*)(zh8 + ((((size_t)mt * 64 + lane) * 64) + mi) * 8) = o;
  } else {
    const int row = (blockIdx.x - N_TOK / 4) * 4 + w;
    const float4* r = (const float4*)(emb + (size_t)row * DIM);
    float4 v0 = r[lane * 2], v1 = r[lane * 2 + 1];
    uint2 o;
    o.x = pack4(v0.x*ESCALE, v0.y*ESCALE, v0.z*ESCALE, v0.w*ESCALE);
    o.y = pack4(v1.x*ESCALE, v1.y*ESCALE, v1.z*ESCALE, v1.w*ESCALE);
    const int ct = row >> 6, ni = row & 63;
    *(uint2*)(eh8 + ((((size_t)ct * 64 + lane) * 64) + ni) * 8) = o;
  }
}

// A-stationary streaming fp8 GEMM.
// grid 1024: mt = bid>>2 (64 rows), q = bid&3 (col quarter). 4 waves; wave w
// streams ct = q*32 + nt*4 + w, nt in [0,8). Private B ring-2, no barriers.
__global__ __launch_bounds__(256, 4)
void vq_mfma(const unsigned char* __restrict__ zh8, const unsigned char* __restrict__ eh8,
             float4* __restrict__ pmx) {
  __shared__ uint2 lB[4][2][512];   // 4 waves x ring2 x 4KB

  const int bid = blockIdx.x;
  const int mt = bid >> 2, q = bid & 3;
  const int tid = threadIdx.x;
  const int w = tid >> 6, lane = tid & 63;
  const int quad = lane >> 4, lc = lane & 15;
  const int m0 = mt * 64;

  // ---- A panel -> registers (64 coalesced b64 loads, static indices) ----
  long long A[16][4];
  const char* gA = (const char*)zh8 + (size_t)mt * 32768;
  #pragma unroll
  for (int ks = 0; ks < 16; ++ks)
    #pragma unroll
    for (int mf = 0; mf < 4; ++mf)
      A[ks][mf] = *(const long long*)(gA + (((ks * 4 + quad) * 64) + mf * 16 + lc) * 8);

  const char* gB = (const char*)eh8;
  auto stage = [&](int g) {                      // g = nt*8 + ch, ring = g&1
    const int nt2 = g >> 3, ch2 = g & 7;
    const char* src = gB + (size_t)(q * 32 + nt2 * 4 + w) * 32768 + ch2 * 4096;
    char* dst = (char*)&lB[w][g & 1][0];
    #pragma unroll
    for (int i = 0; i < 4; ++i)
      GLDS16(src + i * 1024 + lane * 16, dst + i * 1024 + lane * 16);
  };

  stage(0); stage(1);                            // out: 64(A) + 8(B)

  f32x4 C[4][4];
  #pragma unroll
  for (int i = 0; i < 4; ++i)
    #pragma unroll
    for (int j = 0; j < 4; ++j) C[i][j] = (f32x4){0.f, 0.f, 0.f, 0.f};

  for (int nt = 0; nt < NTI; ++nt) {
    #pragma unroll
    for (int ch = 0; ch < 8; ++ch) {
      // counted waits: chunk's 4 loads are oldest; epilogue's 16 stores counted
      if (ch < 2) {
        if (nt == 0) { asm volatile("s_waitcnt vmcnt(4)"  ::: "memory"); }
        else         { asm volatile("s_waitcnt vmcnt(20)" ::: "memory"); }
      } else if (ch == 7) {
        if (nt == NTI - 1) { asm volatile("s_waitcnt vmcnt(0)" ::: "memory"); }
        else               { asm volatile("s_waitcnt vmcnt(4)" ::: "memory"); }
      } else {
        asm volatile("s_waitcnt vmcnt(4)" ::: "memory");
      }
      const uint2* bs = &lB[w][ch & 1][0];
      #pragma unroll
      for (int s = 0; s < 2; ++s) {
        const int kxl = s * 4 + quad;
        long long b0 = __builtin_bit_cast(long long, bs[kxl*64 +  0 + lc]);
        long long b1 = __builtin_bit_cast(long long, bs[kxl*64 + 16 + lc]);
        long long b2 = __builtin_bit_cast(long long, bs[kxl*64 + 32 + lc]);
        long long b3 = __builtin_bit_cast(long long, bs[kxl*64 + 48 + lc]);
        C[0][0] = __builtin_amdgcn_mfma_f32_16x16x32_fp8_fp8(A[ch*2+s][0], b0, C[0][0], 0,0,0);
        C[0][1] = __builtin_amdgcn_mfma_f32_16x16x32_fp8_fp8(A[ch*2+s][0], b1, C[0][1], 0,0,0);
        C[0][2] = __builtin_amdgcn_mfma_f32_16x16x32_fp8_fp8(A[ch*2+s][0], b2, C[0][2], 0,0,0);
        C[0][3] = __builtin_amdgcn_mfma_f32_16x16x32_fp8_fp8(A[ch*2+s][0], b3, C[0][3], 0,0,0);
        C[1][0] = __builtin_amdgcn_mfma_f32_16x16x32_fp8_fp8(A[ch*2+s][1], b0, C[1][0], 0,0,0);
        C[1][1] = __builtin_amdgcn_mfma_f32_16x16x32_fp8_fp8(A[ch*2+s][1], b1, C[1][1], 0,0,0);
        C[1][2] = __builtin_amdgcn_mfma_f32_16x16x32_fp8_fp8(A[ch*2+s][1], b2, C[1][2], 0,0,0);
        C[1][3] = __builtin_amdgcn_mfma_f32_16x16x32_fp8_fp8(A[ch*2+s][1], b3, C[1][3], 0,0,0);
        C[2][0] = __builtin_amdgcn_mfma_f32_16x16x32_fp8_fp8(A[ch*2+s][2], b0, C[2][0], 0,0,0);
        C[2][1] = __builtin_amdgcn_mfma_f32_16x16x32_fp8_fp8(A[ch*2+s][2], b1, C[2][1], 0,0,0);
        C[2][2] = __builtin_amdgcn_mfma_f32_16x16x32_fp8_fp8(A[ch*2+s][2], b2, C[2][2], 0,0,0);
        C[2][3] = __builtin_amdgcn_mfma_f32_16x16x32_fp8_fp8(A[ch*2+s][2], b3, C[2][3], 0,0,0);
        C[3][0] = __builtin_amdgcn_mfma_f32_16x16x32_fp8_fp8(A[ch*2+s][3], b0, C[3][0], 0,0,0);
        C[3][1] = __builtin_amdgcn_mfma_f32_16x16x32_fp8_fp8(A[ch*2+s][3], b1, C[3][1], 0,0,0);
        C[3][2] = __builtin_amdgcn_mfma_f32_16x16x32_fp8_fp8(A[ch*2+s][3], b2, C[3][2], 0,0,0);
        C[3][3] = __builtin_amdgcn_mfma_f32_16x16x32_fp8_fp8(A[ch*2+s][3], b3, C[3][3], 0,0,0);
      }
      {
        const int g2 = nt * 8 + ch + 2;
        if (g2 < NTI * 8) stage(g2);
      }
    }
    // ---- per-tile epilogue: top-2 via DPP allreduce (VALU only, exact v2) ----
    const int ct = q * 32 + nt * 4 + w;
    #pragma unroll
    for (int mf = 0; mf < 4; ++mf)
      #pragma unroll
      for (int rr = 0; rr < 4; ++rr) {
        float v1l = C[mf][0][rr];
        int   k1l = ct * 64 + lc;
        float v2l = -3.4e38f;
        #pragma unroll
        for (int nf = 1; nf < 4; ++nf) {
          float v = C[mf][nf][rr];
          int   k = ct * 64 + nf * 16 + lc;
          if (v > v1l) { v2l = v1l; v1l = v; k1l = k; }
          else         { v2l = fmaxf(v2l, v); }
        }
        // allreduce max over the 16-lane row
        float v1 = v1l;
        v1 = fmaxf(v1, dpp_ror_f<8>(v1));
        v1 = fmaxf(v1, dpp_ror_f<4>(v1));
        v1 = fmaxf(v1, dpp_ror_f<2>(v1));
        v1 = fmaxf(v1, dpp_ror_f<1>(v1));
        // lowest-k argmax
        int kc = (v1l == v1) ? k1l : 0x7fffffff;
        kc = min(kc, dpp_ror_i<8>(kc));
        kc = min(kc, dpp_ror_i<4>(kc));
        kc = min(kc, dpp_ror_i<2>(kc));
        kc = min(kc, dpp_ror_i<1>(kc));
        // second max: winner lane contributes its v2l, others their v1l
        float c2 = (k1l == kc) ? v2l : v1l;
        c2 = fmaxf(c2, dpp_ror_f<8>(c2));
        c2 = fmaxf(c2, dpp_ror_f<4>(c2));
        c2 = fmaxf(c2, dpp_ror_f<2>(c2));
        c2 = fmaxf(c2, dpp_ror_f<1>(c2));
        if (lc == 0) {                         // exactly 16 stores per epilogue
          int row = m0 + mf * 16 + quad * 4 + rr;
          float4 rec;
          rec.x = v1; rec.y = __int_as_float(kc); rec.z = c2; rec.w = 0.f;
          pmx[(size_t)row * NCT + ct] = rec;
        }
      }
    #pragma unroll
    for (int i = 0; i < 4; ++i)
      #pragma unroll
      for (int j = 0; j < 4; ++j) C[i][j] = (f32x4){0.f, 0.f, 0.f, 0.f};
  }
}

// finalize: gmax over 128 tile records; exact-chain k1 candidates (compact list
// + coalesced LDS staging); full 64-code exact scan of v2-trigger tiles, TWO
// tiles per pass with interleaved (bit-exact) chains. Outputs + loss partial.
__global__ __launch_bounds__(256, 3)
void vq_finalize(const float* __restrict__ z, const float* __restrict__ emb,
                 const float* __restrict__ s1g, const float4* __restrict__ pmx,
                 float* __restrict__ out, double* __restrict__ part) {
  __shared__ float4 lstage4[NSTAGE * 129];
  __shared__ int   ck[CLIST];
  __shared__ float cq[CLIST];
  __shared__ unsigned char cmeta[CLIST];
  __shared__ int ccnt;
  __shared__ double lossp[4];

  const int w = threadIdx.x >> 6, l = threadIdx.x & 63;
  const int row = blockIdx.x * 4 + w;
  if (threadIdx.x == 0) ccnt = 0;

  float4 pa = pmx[(size_t)row * NCT + l];
  float4 pb = pmx[(size_t)row * NCT + 64 + l];
  float gm = fmaxf(pa.x, pb.x);
  #pragma unroll
  for (int m = 32; m >= 1; m >>= 1) gm = fmaxf(gm, __shfl_xor(gm, m));
  const float thr = gm - MARGIN_A;
  const float s1 = s1g[row];
  const float4* zw4 = (const float4*)(z + (size_t)row * DIM);

  unsigned long long ta = __ballot(pa.z >= thr);   // v2-trigger tiles 0..63
  unsigned long long tb = __ballot(pb.z >= thr);   // tiles 64..127
  __syncthreads();                                 // ccnt=0 visible

  float qb = 1e30f; int kb = 0x7fffffff;
  for (int half = 0; half < 2; ++half) {
    float v1 = half ? pb.x : pa.x;
    int   k1 = __float_as_int(half ? pb.y : pa.y);
    if (v1 >= thr) {
      int s = atomicAdd(&ccnt, 1);
      if (s < CLIST) { ck[s] = k1; cmeta[s] = (unsigned char)w; }
      else {
        const float4* er4 = (const float4*)(emb + (size_t)k1 * DIM);
        float d = 0.f;
        for (int i4 = 0; i4 < 128; ++i4) {
          float4 zv = zw4[i4], ev = er4[i4];
          d = fmaf(zv.x, ev.x, d); d = fmaf(zv.y, ev.y, d);
          d = fmaf(zv.z, ev.z, d); d = fmaf(zv.w, ev.w, d);
        }
        float q = s1 - 2.f * d;
        if (q < qb || (q == qb && k1 < kb)) { qb = q; kb = k1; }
      }
    }
  }
  __syncthreads();
  int cN = ccnt; if (cN > CLIST) cN = CLIST;
  int sN = cN;   if (sN > NSTAGE) sN = NSTAGE;

  for (int si = w; si < sN; si += 4) {
    const float4* e4 = (const float4*)(emb + (size_t)ck[si] * DIM);
    lstage4[si * 129 + l * 2]     = e4[l * 2];
    lstage4[si * 129 + l * 2 + 1] = e4[l * 2 + 1];
  }
  __syncthreads();

  for (int ci = threadIdx.x; ci < cN; ci += 256) {
    const int k = ck[ci];
    const int r = cmeta[ci];
    const float4* zr4 = (const float4*)(z + (size_t)(blockIdx.x * 4 + r) * DIM);
    const float4* er4 = (ci < NSTAGE) ? (const float4*)&lstage4[ci * 129]
                                      : (const float4*)(emb + (size_t)k * DIM);
    float d = 0.f;
    for (int i4 = 0; i4 < 128; ++i4) {
      float4 zv = zr4[i4], ev = er4[i4];
      d = fmaf(zv.x, ev.x, d); d = fmaf(zv.y, ev.y, d);
      d = fmaf(zv.z, ev.z, d); d = fmaf(zv.w, ev.w, d);
    }
    cq[ci] = s1g[blockIdx.x * 4 + r] - 2.f * d;
  }

  // v2-trigger full scans: TWO tiles per pass, interleaved independent chains.
  for (;;) {
    int t0 = -1, t1 = -1;
    if (ta)      { t0 = __builtin_ctzll(ta); ta &= ta - 1; }
    else if (tb) { t0 = 64 + __builtin_ctzll(tb); tb &= tb - 1; }
    if (t0 < 0) break;
    if (ta)      { t1 = __builtin_ctzll(ta); ta &= ta - 1; }
    else if (tb) { t1 = 64 + __builtin_ctzll(tb); tb &= tb - 1; }
    const int k0 = t0 * 64 + l;
    const float4* e0 = (const float4*)(emb + (size_t)k0 * DIM);
    if (t1 >= 0) {
      const int k1t = t1 * 64 + l;
      const float4* e1 = (const float4*)(emb + (size_t)k1t * DIM);
      float d0 = 0.f, d1 = 0.f;
      for (int i4 = 0; i4 < 128; ++i4) {
        float4 zv = zw4[i4], ev0 = e0[i4], ev1 = e1[i4];
        d0 = fmaf(zv.x, ev0.x, d0); d1 = fmaf(zv.x, ev1.x, d1);
        d0 = fmaf(zv.y, ev0.y, d0); d1 = fmaf(zv.y, ev1.y, d1);
        d0 = fmaf(zv.z, ev0.z, d0); d1 = fmaf(zv.z, ev1.z, d1);
        d0 = fmaf(zv.w, ev0.w, d0); d1 = fmaf(zv.w, ev1.w, d1);
      }
      float q0 = s1 - 2.f * d0, q1 = s1 - 2.f * d1;
      if (q0 < qb || (q0 == qb && k0  < kb)) { qb = q0; kb = k0;  }
      if (q1 < qb || (q1 == qb && k1t < kb)) { qb = q1; kb = k1t; }
    } else {
      float d0 = 0.f;
      for (int i4 = 0; i4 < 128; ++i4) {
        float4 zv = zw4[i4], ev0 = e0[i4];
        d0 = fmaf(zv.x, ev0.x, d0); d0 = fmaf(zv.y, ev0.y, d0);
        d0 = fmaf(zv.z, ev0.z, d0); d0 = fmaf(zv.w, ev0.w, d0);
      }
      float q0 = s1 - 2.f * d0;
      if (q0 < qb || (q0 == qb && k0 < kb)) { qb = q0; kb = k0; }
    }
  }
  __syncthreads();                               // cq ready

  for (int e = l; e < cN; e += 64) {
    if (cmeta[e] == (unsigned char)w) {
      float q = cq[e]; int k = ck[e];
      if (q < qb || (q == qb && k < kb)) { qb = q; kb = k; }
    }
  }
  #pragma unroll
  for (int m = 32; m >= 1; m >>= 1) {
    float qo = __shfl_xor(qb, m); int ko = __shfl_xor(kb, m);
    if (qo < qb || (qo == qb && ko < kb)) { qb = qo; kb = ko; }
  }

  const float4* qr4 = (const float4*)(emb + (size_t)kb * DIM);
  float4 zv0 = zw4[l * 2], zv1 = zw4[l * 2 + 1];
  float4 qv0 = qr4[l * 2], qv1 = qr4[l * 2 + 1];
  float ls = 0.f; float4 ov0, ov1;
  {
    const float* zp=(const float*)&zv0; const float* qp=(const float*)&qv0; float* op=(float*)&ov0;
    #pragma unroll
    for (int e = 0; e < 4; ++e) { float d2 = qp[e]-zp[e]; op[e] = zp[e]+d2; ls += d2*d2; }
  }
  {
    const float* zp=(const float*)&zv1; const float* qp=(const float*)&qv1; float* op=(float*)&ov1;
    #pragma unroll
    for (int e = 0; e < 4; ++e) { float d2 = qp[e]-zp[e]; op[e] = zp[e]+d2; ls += d2*d2; }
  }
  float4* orow = (float4*)(out + (size_t)row * DIM);
  orow[l * 2] = ov0; orow[l * 2 + 1] = ov1;
  #pragma unroll
  for (int m = 32; m >= 1; m >>= 1) ls += __shfl_xor(ls, m);
  if (l == 0) {
    out[(size_t)N_TOK * DIM + 1 + row] = (float)kb;
    lossp[w] = (double)ls;
  }
  __syncthreads();
  if (threadIdx.x == 0)
    part[blockIdx.x] = lossp[0] + lossp[1] + lossp[2] + lossp[3];
}

// reduce 4096 per-block partials -> loss scalar
__global__ void vq_loss(const double* __restrict__ part, float* __restrict__ out) {
  __shared__ double ws[4];
  const int t = threadIdx.x, w = t >> 6, lane = t & 63;
  double s = 0.0;
  #pragma unroll
  for (int i = 0; i < 16; ++i) s += part[t + i * 256];
  #pragma unroll
  for (int m = 32; m >= 1; m >>= 1) s += __shfl_xor(s, m);
  if (lane == 0) ws[w] = s;
  __syncthreads();
  if (t == 0) {
    double tot = ws[0] + ws[1] + ws[2] + ws[3];
    out[(size_t)N_TOK * DIM] =
        (float)(tot * (1.0 + (double)BETA) / ((double)N_TOK * (double)DIM));
  }
}

extern "C" void kernel_launch(void* const* d_in, const int* in_sizes, int n_in,
                              void* d_out, int out_size, void* d_ws, size_t ws_size,
                              hipStream_t stream) {
  const float* z   = (const float*)d_in[0];
  const float* emb = (const float*)d_in[1];
  float* out = (float*)d_out;
  char* ws = (char*)d_ws;
  float4*        pmx  = (float4*)(ws + WS_PMX);
  float*         s1   = (float*)(ws + WS_S1);
  double*        part = (double*)(ws + WS_PART);
  unsigned char* zh8  = (unsigned char*)(ws + WS_ZH);
  unsigned char* eh8  = (unsigned char*)(ws + WS_EH);

  vq_pack<<<N_TOK / 4 + NEMB / 4, 256, 0, stream>>>(z, emb, zh8, eh8, s1);
  vq_mfma<<<1024, 256, 0, stream>>>(zh8, eh8, pmx);
  vq_finalize<<<N_TOK / 4, 256, 0, stream>>>(z, emb, s1, pmx, out, part);
  vq_loss<<<1, 256, 0, stream>>>(part, out);
}

// Round 23
// 259.470 us; speedup vs baseline: 1.4028x; 1.4028x over previous
//
#include <hip/hip_runtime.h>

// VectorQuantizer: z [16,1024,512] f32, emb [8192,512] f32
// out: [z_q_st (16384*512 f32)][total_loss (1 f32)][idx as f32 (16384)]
//
// Round 23 = best-known recombination, all components measured:
//  - GEMM: R20 exactly (A-stationary fp8, grid 512, launch_bounds(256,2) --
//    R22 proved (256,4) demotes the A panel out of registers (VGPR 64, FETCH
//    606MB, 256us); no setprio -- R21 proved -4%; DPP-allreduce top-2 epilogue,
//    16B float4 records). Measured 150.5us, MfmaUtil 39% (~2.3x the 66us
//    MFMA-pipe floor; latency-interleave regime).
//  - finalize: R21's paired trigger scans (bit-exact chains, cross-candidate
//    ILP only). Measured ~92us class.
// Exact-idx machinery (12 rounds proven): q = fl(s1 - 2*dot) with strict
// d-ascending fmaf chain, lowest-k ties; k1 candidates + full 64-code scan of
// v2-trigger tiles => complete coverage.

#define N_TOK 16384
#define DIM   512
#define NEMB  8192
#define BETA  0.25f
#define NCT   128            // 64-wide column tiles
#define MARGIN_A 2.4f        // scaled units (acc = 4096*dot); ~8.9 sigma_pair
#define ESCALE 4096.0f
#define NSTAGE 24
#define CLIST  96

using f32x4 = __attribute__((ext_vector_type(4))) float;

// ---- ws layout (bytes), total ~44.1 MB ----
#define WS_PMX  0                                  // float4[N_TOK*NCT] = 32MB
#define WS_S1   ((size_t)N_TOK*NCT*16)
#define WS_PART (WS_S1 + N_TOK*4)
#define WS_ZH   (WS_PART + (N_TOK/4)*8)
#define WS_EH   (WS_ZH + (size_t)N_TOK*DIM)

#define GLDS16(g, l) __builtin_amdgcn_global_load_lds( \
    (const __attribute__((address_space(1))) void*)(g), \
    (__attribute__((address_space(3))) void*)(l), 16, 0, 0)

template <int N>
__device__ inline int dpp_ror_i(int v) {            // row_ror:N (16-lane row)
  return __builtin_amdgcn_update_dpp(0, v, 0x120 + N, 0xF, 0xF, false);
}
template <int N>
__device__ inline float dpp_ror_f(float v) {
  return __builtin_bit_cast(float, dpp_ror_i<N>(__builtin_bit_cast(int, v)));
}

// RNE float -> OCP e4m3fn byte (|f| < 448; handles subnormals).
__device__ inline unsigned f2e4m3(float f) {
  unsigned u = __builtin_bit_cast(unsigned, f);
  unsigned s = (u >> 24) & 0x80u;
  float a = __builtin_bit_cast(float, u & 0x7fffffffu);
  if (a < 0.015625f) {
    unsigned q = (unsigned)rintf(a * 512.0f);
    return s | q;
  }
  unsigned m = u & 0x7fffffffu;
  m += 0x7ffffu + ((m >> 20) & 1u);
  unsigned e = (m >> 23) - 127u + 7u;
  return s | (e << 3) | ((m >> 20) & 7u);
}

__device__ inline unsigned pack4(float a, float b, float c, float d) {
  return f2e4m3(a) | (f2e4m3(b) << 8) | (f2e4m3(c) << 16) | (f2e4m3(d) << 24);
}

// Fused pack. zh8: [mt(256)][kc(64)][mi(64)] 8B-units; eh8: [ct(128)][kc(64)][ni(64)].
__global__ void vq_pack(const float* __restrict__ z, const float* __restrict__ emb,
                        unsigned char* __restrict__ zh8, unsigned char* __restrict__ eh8,
                        float* __restrict__ s1) {
  const int w = threadIdx.x >> 6, lane = threadIdx.x & 63;
  if (blockIdx.x < N_TOK / 4) {
    const int row = blockIdx.x * 4 + w;
    const float4* r = (const float4*)(z + (size_t)row * DIM);
    float4 v0 = r[lane * 2], v1 = r[lane * 2 + 1];
    // s1: bit-identical to the round-2 proven path
    float p0=v0.x*v0.x, p1=v0.y*v0.y, p2=v0.z*v0.z, p3=v0.w*v0.w;
    float p4=v1.x*v1.x, p5=v1.y*v1.y, p6=v1.z*v1.z, p7=v1.w*v1.w;
    double s = (double)p0+(double)p1+(double)p2+(double)p3
             + (double)p4+(double)p5+(double)p6+(double)p7;
    #pragma unroll
    for (int m = 32; m >= 1; m >>= 1) s += __shfl_xor(s, m);
    if (lane == 0) s1[row] = (float)s;
    uint2 o;
    o.x = pack4(v0.x, v0.y, v0.z, v0.w);
    o.y = pack4(v1.x, v1.y, v1.z, v1.w);
    const int mt = row >> 6, mi = row & 63;   // kc == lane
    *(uint2*)(zh8 + ((((size_t)mt * 64 + lane) * 64) + mi) * 8) = o;
  } else {
    const int row = (blockIdx.x - N_TOK / 4) * 4 + w;
    const float4* r = (const float4*)(emb + (size_t)row * DIM);
    float4 v0 = r[lane * 2], v1 = r[lane * 2 + 1];
    uint2 o;
    o.x = pack4(v0.x*ESCALE, v0.y*ESCALE, v0.z*ESCALE, v0.w*ESCALE);
    o.y = pack4(v1.x*ESCALE, v1.y*ESCALE, v1.z*ESCALE, v1.w*ESCALE);
    const int ct = row >> 6, ni = row & 63;
    *(uint2*)(eh8 + ((((size_t)ct * 64 + lane) * 64) + ni) * 8) = o;
  }
}

// A-stationary streaming fp8 GEMM (R20 exactly).
// grid 512: mt = bid>>1 (64 rows), h = bid&1 (col half). 4 waves; wave w streams
// col-tiles ct = h*64 + nt*4 + w, nt in [0,16). Private B ring-2, no barriers.
__global__ __launch_bounds__(256, 2)
void vq_mfma(const unsigned char* __restrict__ zh8, const unsigned char* __restrict__ eh8,
             float4* __restrict__ pmx) {
  __shared__ uint2 lB[4][2][512];   // 4 waves x ring2 x 4KB

  const int bid = blockIdx.x;
  const int mt = bid >> 1, h = bid & 1;
  const int tid = threadIdx.x;
  const int w = tid >> 6, lane = tid & 63;
  const int quad = lane >> 4, lc = lane & 15;
  const int m0 = mt * 64;

  // ---- A panel -> registers (64 coalesced b64 loads, static indices) ----
  long long A[16][4];
  const char* gA = (const char*)zh8 + (size_t)mt * 32768;
  #pragma unroll
  for (int ks = 0; ks < 16; ++ks)
    #pragma unroll
    for (int mf = 0; mf < 4; ++mf)
      A[ks][mf] = *(const long long*)(gA + (((ks * 4 + quad) * 64) + mf * 16 + lc) * 8);

  const char* gB = (const char*)eh8;
  auto stage = [&](int g) {                      // g = nt*8 + ch, ring = g&1
    const int nt2 = g >> 3, ch2 = g & 7;
    const char* src = gB + (size_t)(h * 64 + nt2 * 4 + w) * 32768 + ch2 * 4096;
    char* dst = (char*)&lB[w][g & 1][0];
    #pragma unroll
    for (int i = 0; i < 4; ++i)
      GLDS16(src + i * 1024 + lane * 16, dst + i * 1024 + lane * 16);
  };

  stage(0); stage(1);                            // out: 64(A) + 8(B)

  f32x4 C[4][4];
  #pragma unroll
  for (int i = 0; i < 4; ++i)
    #pragma unroll
    for (int j = 0; j < 4; ++j) C[i][j] = (f32x4){0.f, 0.f, 0.f, 0.f};

  for (int nt = 0; nt < 16; ++nt) {
    #pragma unroll
    for (int ch = 0; ch < 8; ++ch) {
      // counted waits: chunk's 4 loads are oldest; epilogue's 16 stores counted
      if (ch < 2) {
        if (nt == 0) { asm volatile("s_waitcnt vmcnt(4)"  ::: "memory"); }
        else         { asm volatile("s_waitcnt vmcnt(20)" ::: "memory"); }
      } else if (ch == 7) {
        if (nt == 15) { asm volatile("s_waitcnt vmcnt(0)" ::: "memory"); }
        else          { asm volatile("s_waitcnt vmcnt(4)" ::: "memory"); }
      } else {
        asm volatile("s_waitcnt vmcnt(4)" ::: "memory");
      }
      const uint2* bs = &lB[w][ch & 1][0];
      #pragma unroll
      for (int s = 0; s < 2; ++s) {
        const int kxl = s * 4 + quad;
        long long b0 = __builtin_bit_cast(long long, bs[kxl*64 +  0 + lc]);
        long long b1 = __builtin_bit_cast(long long, bs[kxl*64 + 16 + lc]);
        long long b2 = __builtin_bit_cast(long long, bs[kxl*64 + 32 + lc]);
        long long b3 = __builtin_bit_cast(long long, bs[kxl*64 + 48 + lc]);
        C[0][0] = __builtin_amdgcn_mfma_f32_16x16x32_fp8_fp8(A[ch*2+s][0], b0, C[0][0], 0,0,0);
        C[0][1] = __builtin_amdgcn_mfma_f32_16x16x32_fp8_fp8(A[ch*2+s][0], b1, C[0][1], 0,0,0);
        C[0][2] = __builtin_amdgcn_mfma_f32_16x16x32_fp8_fp8(A[ch*2+s][0], b2, C[0][2], 0,0,0);
        C[0][3] = __builtin_amdgcn_mfma_f32_16x16x32_fp8_fp8(A[ch*2+s][0], b3, C[0][3], 0,0,0);
        C[1][0] = __builtin_amdgcn_mfma_f32_16x16x32_fp8_fp8(A[ch*2+s][1], b0, C[1][0], 0,0,0);
        C[1][1] = __builtin_amdgcn_mfma_f32_16x16x32_fp8_fp8(A[ch*2+s][1], b1, C[1][1], 0,0,0);
        C[1][2] = __builtin_amdgcn_mfma_f32_16x16x32_fp8_fp8(A[ch*2+s][1], b2, C[1][2], 0,0,0);
        C[1][3] = __builtin_amdgcn_mfma_f32_16x16x32_fp8_fp8(A[ch*2+s][1], b3, C[1][3], 0,0,0);
        C[2][0] = __builtin_amdgcn_mfma_f32_16x16x32_fp8_fp8(A[ch*2+s][2], b0, C[2][0], 0,0,0);
        C[2][1] = __builtin_amdgcn_mfma_f32_16x16x32_fp8_fp8(A[ch*2+s][2], b1, C[2][1], 0,0,0);
        C[2][2] = __builtin_amdgcn_mfma_f32_16x16x32_fp8_fp8(A[ch*2+s][2], b2, C[2][2], 0,0,0);
        C[2][3] = __builtin_amdgcn_mfma_f32_16x16x32_fp8_fp8(A[ch*2+s][2], b3, C[2][3], 0,0,0);
        C[3][0] = __builtin_amdgcn_mfma_f32_16x16x32_fp8_fp8(A[ch*2+s][3], b0, C[3][0], 0,0,0);
        C[3][1] = __builtin_amdgcn_mfma_f32_16x16x32_fp8_fp8(A[ch*2+s][3], b1, C[3][1], 0,0,0);
        C[3][2] = __builtin_amdgcn_mfma_f32_16x16x32_fp8_fp8(A[ch*2+s][3], b2, C[3][2], 0,0,0);
        C[3][3] = __builtin_amdgcn_mfma_f32_16x16x32_fp8_fp8(A[ch*2+s][3], b3, C[3][3], 0,0,0);
      }
      {
        const int g2 = nt * 8 + ch + 2;
        if (g2 < 128) stage(g2);
      }
    }
    // ---- per-tile epilogue: top-2 via DPP allreduce (VALU only, exact v2) ----
    const int ct = h * 64 + nt * 4 + w;
    #pragma unroll
    for (int mf = 0; mf < 4; ++mf)
      #pragma unroll
      for (int rr = 0; rr < 4; ++rr) {
        float v1l = C[mf][0][rr];
        int   k1l = ct * 64 + lc;
        float v2l = -3.4e38f;
        #pragma unroll
        for (int nf = 1; nf < 4; ++nf) {
          float v = C[mf][nf][rr];
          int   k = ct * 64 + nf * 16 + lc;
          if (v > v1l) { v2l = v1l; v1l = v; k1l = k; }
          else         { v2l = fmaxf(v2l, v); }
        }
        // allreduce max over the 16-lane row
        float v1 = v1l;
        v1 = fmaxf(v1, dpp_ror_f<8>(v1));
        v1 = fmaxf(v1, dpp_ror_f<4>(v1));
        v1 = fmaxf(v1, dpp_ror_f<2>(v1));
        v1 = fmaxf(v1, dpp_ror_f<1>(v1));
        // lowest-k argmax
        int kc = (v1l == v1) ? k1l : 0x7fffffff;
        kc = min(kc, dpp_ror_i<8>(kc));
        kc = min(kc, dpp_ror_i<4>(kc));
        kc = min(kc, dpp_ror_i<2>(kc));
        kc = min(kc, dpp_ror_i<1>(kc));
        // second max: winner lane contributes its v2l, others their v1l
        float c2 = (k1l == kc) ? v2l : v1l;
        c2 = fmaxf(c2, dpp_ror_f<8>(c2));
        c2 = fmaxf(c2, dpp_ror_f<4>(c2));
        c2 = fmaxf(c2, dpp_ror_f<2>(c2));
        c2 = fmaxf(c2, dpp_ror_f<1>(c2));
        if (lc == 0) {                         // exactly 16 stores per epilogue
          int row = m0 + mf * 16 + quad * 4 + rr;
          float4 rec;
          rec.x = v1; rec.y = __int_as_float(kc); rec.z = c2; rec.w = 0.f;
          pmx[(size_t)row * NCT + ct] = rec;
        }
      }
    #pragma unroll
    for (int i = 0; i < 4; ++i)
      #pragma unroll
      for (int j = 0; j < 4; ++j) C[i][j] = (f32x4){0.f, 0.f, 0.f, 0.f};
  }
}

// finalize (R21): gmax over 128 tile records; exact-chain k1 candidates (compact
// list + coalesced LDS staging); full 64-code exact scan of v2-trigger tiles,
// TWO tiles per pass with interleaved (bit-exact) chains. Outputs + loss partial.
__global__ __launch_bounds__(256, 3)
void vq_finalize(const float* __restrict__ z, const float* __restrict__ emb,
                 const float* __restrict__ s1g, const float4* __restrict__ pmx,
                 float* __restrict__ out, double* __restrict__ part) {
  __shared__ float4 lstage4[NSTAGE * 129];
  __shared__ int   ck[CLIST];
  __shared__ float cq[CLIST];
  __shared__ unsigned char cmeta[CLIST];
  __shared__ int ccnt;
  __shared__ double lossp[4];

  const int w = threadIdx.x >> 6, l = threadIdx.x & 63;
  const int row = blockIdx.x * 4 + w;
  if (threadIdx.x == 0) ccnt = 0;

  float4 pa = pmx[(size_t)row * NCT + l];
  float4 pb = pmx[(size_t)row * NCT + 64 + l];
  float gm = fmaxf(pa.x, pb.x);
  #pragma unroll
  for (int m = 32; m >= 1; m >>= 1) gm = fmaxf(gm, __shfl_xor(gm, m));
  const float thr = gm - MARGIN_A;
  const float s1 = s1g[row];
  const float4* zw4 = (const float4*)(z + (size_t)row * DIM);

  unsigned long long ta = __ballot(pa.z >= thr);   // v2-trigger tiles 0..63
  unsigned long long tb = __ballot(pb.z >= thr);   // tiles 64..127
  __syncthreads();                                 // ccnt=0 visible

  float qb = 1e30f; int kb = 0x7fffffff;
  for (int half = 0; half < 2; ++half) {
    float v1 = half ? pb.x : pa.x;
    int   k1 = __float_as_int(half ? pb.y : pa.y);
    if (v1 >= thr) {
      int s = atomicAdd(&ccnt, 1);
      if (s < CLIST) { ck[s] = k1; cmeta[s] = (unsigned char)w; }
      else {
        const float4* er4 = (const float4*)(emb + (size_t)k1 * DIM);
        float d = 0.f;
        for (int i4 = 0; i4 < 128; ++i4) {
          float4 zv = zw4[i4], ev = er4[i4];
          d = fmaf(zv.x, ev.x, d); d = fmaf(zv.y, ev.y, d);
          d = fmaf(zv.z, ev.z, d); d = fmaf(zv.w, ev.w, d);
        }
        float q = s1 - 2.f * d;
        if (q < qb || (q == qb && k1 < kb)) { qb = q; kb = k1; }
      }
    }
  }
  __syncthreads();
  int cN = ccnt; if (cN > CLIST) cN = CLIST;
  int sN = cN;   if (sN > NSTAGE) sN = NSTAGE;

  for (int si = w; si < sN; si += 4) {
    const float4* e4 = (const float4*)(emb + (size_t)ck[si] * DIM);
    lstage4[si * 129 + l * 2]     = e4[l * 2];
    lstage4[si * 129 + l * 2 + 1] = e4[l * 2 + 1];
  }
  __syncthreads();

  for (int ci = threadIdx.x; ci < cN; ci += 256) {
    const int k = ck[ci];
    const int r = cmeta[ci];
    const float4* zr4 = (const float4*)(z + (size_t)(blockIdx.x * 4 + r) * DIM);
    const float4* er4 = (ci < NSTAGE) ? (const float4*)&lstage4[ci * 129]
                                      : (const float4*)(emb + (size_t)k * DIM);
    float d = 0.f;
    for (int i4 = 0; i4 < 128; ++i4) {
      float4 zv = zr4[i4], ev = er4[i4];
      d = fmaf(zv.x, ev.x, d); d = fmaf(zv.y, ev.y, d);
      d = fmaf(zv.z, ev.z, d); d = fmaf(zv.w, ev.w, d);
    }
    cq[ci] = s1g[blockIdx.x * 4 + r] - 2.f * d;
  }

  // v2-trigger full scans: TWO tiles per pass, interleaved independent chains.
  for (;;) {
    int t0 = -1, t1 = -1;
    if (ta)      { t0 = __builtin_ctzll(ta); ta &= ta - 1; }
    else if (tb) { t0 = 64 + __builtin_ctzll(tb); tb &= tb - 1; }
    if (t0 < 0) break;
    if (ta)      { t1 = __builtin_ctzll(ta); ta &= ta - 1; }
    else if (tb) { t1 = 64 + __builtin_ctzll(tb); tb &= tb - 1; }
    const int k0 = t0 * 64 + l;
    const float4* e0 = (const float4*)(emb + (size_t)k0 * DIM);
    if (t1 >= 0) {
      const int k1t = t1 * 64 + l;
      const float4* e1 = (const float4*)(emb + (size_t)k1t * DIM);
      float d0 = 0.f, d1 = 0.f;
      for (int i4 = 0; i4 < 128; ++i4) {
        float4 zv = zw4[i4], ev0 = e0[i4], ev1 = e1[i4];
        d0 = fmaf(zv.x, ev0.x, d0); d1 = fmaf(zv.x, ev1.x, d1);
        d0 = fmaf(zv.y, ev0.y, d0); d1 = fmaf(zv.y, ev1.y, d1);
        d0 = fmaf(zv.z, ev0.z, d0); d1 = fmaf(zv.z, ev1.z, d1);
        d0 = fmaf(zv.w, ev0.w, d0); d1 = fmaf(zv.w, ev1.w, d1);
      }
      float q0 = s1 - 2.f * d0, q1 = s1 - 2.f * d1;
      if (q0 < qb || (q0 == qb && k0  < kb)) { qb = q0; kb = k0;  }
      if (q1 < qb || (q1 == qb && k1t < kb)) { qb = q1; kb = k1t; }
    } else {
      float d0 = 0.f;
      for (int i4 = 0; i4 < 128; ++i4) {
        float4 zv = zw4[i4], ev0 = e0[i4];
        d0 = fmaf(zv.x, ev0.x, d0); d0 = fmaf(zv.y, ev0.y, d0);
        d0 = fmaf(zv.z, ev0.z, d0); d0 = fmaf(zv.w, ev0.w, d0);
      }
      float q0 = s1 - 2.f * d0;
      if (q0 < qb || (q0 == qb && k0 < kb)) { qb = q0; kb = k0; }
    }
  }
  __syncthreads();                               // cq ready

  for (int e = l; e < cN; e += 64) {
    if (cmeta[e] == (unsigned char)w) {
      float q = cq[e]; int k = ck[e];
      if (q < qb || (q == qb && k < kb)) { qb = q; kb = k; }
    }
  }
  #pragma unroll
  for (int m = 32; m >= 1; m >>= 1) {
    float qo = __shfl_xor(qb, m); int ko = __shfl_xor(kb, m);
    if (qo < qb || (qo == qb && ko < kb)) { qb = qo; kb = ko; }
  }

  const float4* qr4 = (const float4*)(emb + (size_t)kb * DIM);
  float4 zv0 = zw4[l * 2], zv1 = zw4[l * 2 + 1];
  float4 qv0 = qr4[l * 2], qv1 = qr4[l * 2 + 1];
  float ls = 0.f; float4 ov0, ov1;
  {
    const float* zp=(const float*)&zv0; const float* qp=(const float*)&qv0; float* op=(float*)&ov0;
    #pragma unroll
    for (int e = 0; e < 4; ++e) { float d2 = qp[e]-zp[e]; op[e] = zp[e]+d2; ls += d2*d2; }
  }
  {
    const float* zp=(const float*)&zv1; const float* qp=(const float*)&qv1; float* op=(float*)&ov1;
    #pragma unroll
    for (int e = 0; e < 4; ++e) { float d2 = qp[e]-zp[e]; op[e] = zp[e]+d2; ls += d2*d2; }
  }
  float4* orow = (float4*)(out + (size_t)row * DIM);
  orow[l * 2] = ov0; orow[l * 2 + 1] = ov1;
  #pragma unroll
  for (int m = 32; m >= 1; m >>= 1) ls += __shfl_xor(ls, m);
  if (l == 0) {
    out[(size_t)N_TOK * DIM + 1 + row] = (float)kb;
    lossp[w] = (double)ls;
  }
  __syncthreads();
  if (threadIdx.x == 0)
    part[blockIdx.x] = lossp[0] + lossp[1] + lossp[2] + lossp[3];
}

// reduce 4096 per-block partials -> loss scalar
__global__ void vq_loss(const double* __restrict__ part, float* __restrict__ out) {
  __shared__ double ws[4];
  const int t = threadIdx.x, w = t >> 6, lane = t & 63;
  double s = 0.0;
  #pragma unroll
  for (int i = 0; i < 16; ++i) s += part[t + i * 256];
  #pragma unroll
  for (int m = 32; m >= 1; m >>= 1) s += __shfl_xor(s, m);
  if (lane == 0) ws[w] = s;
  __syncthreads();
  if (t == 0) {
    double tot = ws[0] + ws[1] + ws[2] + ws[3];
    out[(size_t)N_TOK * DIM] =
        (float)(tot * (1.0 + (double)BETA) / ((double)N_TOK * (double)DIM));
  }
}

extern "C" void kernel_launch(void* const* d_in, const int* in_sizes, int n_in,
                              void* d_out, int out_size, void* d_ws, size_t ws_size,
                              hipStream_t stream) {
  const float* z   = (const float*)d_in[0];
  const float* emb = (const float*)d_in[1];
  float* out = (float*)d_out;
  char* ws = (char*)d_ws;
  float4*        pmx  = (float4*)(ws + WS_PMX);
  float*         s1   = (float*)(ws + WS_S1);
  double*        part = (double*)(ws + WS_PART);
  unsigned char* zh8  = (unsigned char*)(ws + WS_ZH);
  unsigned char* eh8  = (unsigned char*)(ws + WS_EH);

  vq_pack<<<N_TOK / 4 + NEMB / 4, 256, 0, stream>>>(z, emb, zh8, eh8, s1);
  vq_mfma<<<512, 256, 0, stream>>>(zh8, eh8, pmx);
  vq_finalize<<<N_TOK / 4, 256, 0, stream>>>(z, emb, s1, pmx, out, part);
  vq_loss<<<1, 256, 0, stream>>>(part, out);
}